// Round 3
// baseline (5352.489 us; speedup 1.0000x reference)
//
#include <hip/hip_runtime.h>
#include <hip/hip_bf16.h>

#define BB 4
#define NN 4096
#define DD 256
#define RR 64
#define KK 16
#define TM 16   // rows per projection block

typedef __attribute__((ext_vector_type(8))) short bf16x8;
typedef __attribute__((ext_vector_type(4))) float f32x4;

__device__ __forceinline__ void f32_split(float x, ushort* h, ushort* l){
  __hip_bfloat16 hb = __float2bfloat16(x);
  float hf = __bfloat162float(hb);
  __hip_bfloat16 lb = __float2bfloat16(x - hf);
  *h = *(ushort*)&hb; *l = *(ushort*)&lb;
}

// ---------------- signed softmax over 4096 (block per row, 1024 thr) ----------------
__global__ void __launch_bounds__(1024) ssm_kernel(
    const float* __restrict__ xf, long xf_stride,
    const float* __restrict__ add, long add_stride,
    float* __restrict__ outf, long outf_stride)
{
  __shared__ float sm[32];
  int t = threadIdx.x;
  long b = blockIdx.x;
  float x[4]; float mx = 0.f;
  #pragma unroll
  for (int j=0;j<4;j++){
    int i = t + j*1024;
    float v = xf[b*xf_stride + i];
    if (add) v += add[b*add_stride + i];
    x[j]=v; mx = fmaxf(mx, fabsf(v));
  }
  #pragma unroll
  for (int o=1;o<64;o<<=1) mx = fmaxf(mx, __shfl_xor(mx,o,64));
  int wid = t>>6;
  if ((t&63)==0) sm[wid]=mx;
  __syncthreads();
  mx = sm[0];
  #pragma unroll
  for (int w=1;w<16;w++) mx = fmaxf(mx, sm[w]);
  float e[4]; float ssum=0.f;
  #pragma unroll
  for (int j=0;j<4;j++){ e[j]=expf(fabsf(x[j])-mx); ssum+=e[j]; }
  #pragma unroll
  for (int o=1;o<64;o<<=1) ssum += __shfl_xor(ssum,o,64);
  if ((t&63)==0) sm[16+wid]=ssum;
  __syncthreads();
  ssum = sm[16];
  #pragma unroll
  for (int w=1;w<16;w++) ssum += sm[16+w];
  float inv = 1.0f/ssum;
  #pragma unroll
  for (int j=0;j<4;j++){
    int i = t + j*1024;
    float sg = (x[j]>0.f)?1.f:((x[j]<0.f)?-1.f:0.f);
    outf[b*outf_stride + i] = sg*e[j]*inv;
  }
}

// ------ projection with 0/1/2 inline layernorms: out = ln^nln(src) @ [U|V] ------
// Optionally also writes the normalized rows (NV) and per-row 1/(||x||+1e-6)
// (NRM) so gather_kernel never re-does per-message LN / norm reductions.
__global__ void __launch_bounds__(256) proj_ln_kernel(
    const float* __restrict__ src,
    const float* __restrict__ lg, const float* __restrict__ lb, int nln,
    const float* __restrict__ U, ushort* __restrict__ oUh, ushort* __restrict__ oUl, float scaleU,
    const float* __restrict__ V, ushort* __restrict__ oVh, ushort* __restrict__ oVl, float scaleV,
    float* __restrict__ nvout, float* __restrict__ nrmout)
{
  __shared__ float xs[TM][DD];     // 16 KB
  __shared__ float ut[64*64];      // 16 KB
  __shared__ float vt[64*64];      // 16 KB
  int t = threadIdx.x;
  int wid = t>>6, lane = t&63;
  long row0 = (long)blockIdx.x*TM;

  float gv[4], bv[4];
  if (nln){
    #pragma unroll
    for (int u=0;u<4;u++){ int d=u*64+lane; gv[u]=lg[d]; bv[u]=lb[d]; }
  }
  for (int rr=0; rr<4; rr++){
    int r = wid*4 + rr;
    const float* srow = src + (row0 + r)*DD;
    float x[4];
    #pragma unroll
    for (int u=0;u<4;u++) x[u] = srow[u*64 + lane];
    for (int p=0;p<nln;p++){
      float s=0.f,q=0.f;
      #pragma unroll
      for (int u=0;u<4;u++){ s+=x[u]; q+=x[u]*x[u]; }
      #pragma unroll
      for (int o=1;o<64;o<<=1){ s+=__shfl_xor(s,o,64); q+=__shfl_xor(q,o,64); }
      float m = s*(1.f/DD), var = q*(1.f/DD)-m*m, rstd = rsqrtf(var+1e-5f);
      #pragma unroll
      for (int u=0;u<4;u++) x[u] = (x[u]-m)*rstd*gv[u]+bv[u];
    }
    if (nrmout){
      float ss=0.f;
      #pragma unroll
      for (int u=0;u<4;u++) ss += x[u]*x[u];
      #pragma unroll
      for (int o=1;o<64;o<<=1) ss += __shfl_xor(ss,o,64);
      if (lane==0) nrmout[row0 + r] = 1.f/(sqrtf(ss)+1e-6f);
    }
    if (nvout){
      #pragma unroll
      for (int u=0;u<4;u++) nvout[(row0 + r)*DD + u*64 + lane] = x[u];
    }
    #pragma unroll
    for (int u=0;u<4;u++) xs[r][u*64+lane] = x[u];
  }
  __syncthreads();

  float aU[4] = {0.f,0.f,0.f,0.f};
  float aV[4] = {0.f,0.f,0.f,0.f};
  for (int kt=0; kt<4; kt++){
    const float4* Ut = (const float4*)(U + (long)kt*64*RR);
    #pragma unroll
    for (int i=0;i<4;i++) ((float4*)ut)[i*256 + t] = Ut[i*256 + t];
    if (V){
      const float4* Vt = (const float4*)(V + (long)kt*64*RR);
      #pragma unroll
      for (int i=0;i<4;i++) ((float4*)vt)[i*256 + t] = Vt[i*256 + t];
    }
    __syncthreads();
    #pragma unroll 4
    for (int dd=0; dd<64; dd+=4){
      float4 xq[4];
      #pragma unroll
      for (int r=0;r<4;r++) xq[r] = *(const float4*)&xs[wid*4+r][kt*64+dd];
      #pragma unroll
      for (int j=0;j<4;j++){
        float uv = ut[(dd+j)*64 + lane];
        float vv = V ? vt[(dd+j)*64 + lane] : 0.f;
        #pragma unroll
        for (int r=0;r<4;r++){
          float xv = (j==0)?xq[r].x:(j==1)?xq[r].y:(j==2)?xq[r].z:xq[r].w;
          aU[r] += xv*uv;
          if (V) aV[r] += xv*vv;
        }
      }
    }
    __syncthreads();
  }
  #pragma unroll
  for (int r=0;r<4;r++){
    long row = row0 + wid*4 + r;
    ushort h, l;
    f32_split(aU[r]*scaleU, &h, &l);
    oUh[row*RR + lane] = h; oUl[row*RR + lane] = l;
    if (V){
      f32_split(aV[r]*scaleV, &h, &l);
      oVh[row*RR + lane] = h; oVl[row*RR + lane] = l;
    }
  }
}

// ---- FUSED score GEMM + top-16: never materializes the NxN score matrix ----
// Block = 64 dst rows, 4 waves. Per 128-src slab, wave w computes a 64x32
// MFMA tile (cols [w*32, w*32+32)), writes it to its private LDS column
// slice, then lane=row scans its 32 values against a register-held running
// 16th-best bound (Tk,Ti) with rare sorted-inserts into a per-wave LDS
// top-16 list. No intra-loop barriers (all LDS regions wave-private).
// Final: 4-way merge of the sorted partial lists -> exact (|v| desc, idx asc)
// top-16, identical selection + output order to the old chunked topk.
__global__ void __launch_bounds__(256) score_topk(
    const ushort* __restrict__ dph, const ushort* __restrict__ dpl, long dp_bs,
    const ushort* __restrict__ sph, const ushort* __restrict__ spl,
    float* __restrict__ wout, int* __restrict__ iout)
{
  __shared__ float sc[64][129];        // stride 129: (lane+c)%32 -> conflict-free
  __shared__ float topV[4][64][16];
  __shared__ int   topI[4][64][16];
  const int b = blockIdx.y;
  const int t = threadIdx.x;
  const int w = t>>6, lane = t&63;
  const int row16 = lane & 15, quad = lane >> 4;
  const long dst0 = (long)blockIdx.x*64;

  // loop-invariant A fragments (64 dst rows of this block)
  const ushort* Ahp = dph + (long)b*dp_bs + (dst0 + row16)*RR + quad*8;
  const ushort* Alp = dpl + (long)b*dp_bs + (dst0 + row16)*RR + quad*8;
  bf16x8 ah[4][2], al[4][2];
  #pragma unroll
  for (int mi=0;mi<4;mi++){
    #pragma unroll
    for (int s=0;s<2;s++){
      ah[mi][s] = *(const bf16x8*)(Ahp + (long)mi*16*RR + s*32);
      al[mi][s] = *(const bf16x8*)(Alp + (long)mi*16*RR + s*32);
    }
  }

  #pragma unroll
  for (int e=0;e<16;e++){ topV[w][lane][e]=0.f; topI[w][lane][e]=0x7fffffff; }
  float Tk = -1.f; int Ti = 0x7fffffff;

  const ushort* Bh0 = sph + (long)b*NN*RR + (long)(w*32 + row16)*RR + quad*8;
  const ushort* Bl0 = spl + (long)b*NN*RR + (long)(w*32 + row16)*RR + quad*8;

#define LOADB(BH,BL,IT) { \
    _Pragma("unroll") \
    for (int ni=0;ni<2;ni++){ \
      _Pragma("unroll") \
      for (int s=0;s<2;s++){ \
        BH[ni][s] = *(const bf16x8*)(Bh0 + (long)(IT)*128*RR + (long)ni*16*RR + s*32); \
        BL[ni][s] = *(const bf16x8*)(Bl0 + (long)(IT)*128*RR + (long)ni*16*RR + s*32); \
      } \
    } }

#define PROCESS(BH,BL,IT) { \
    f32x4 acc[4][2]; \
    _Pragma("unroll") \
    for (int mi=0;mi<4;mi++){ \
      _Pragma("unroll") \
      for (int ni=0;ni<2;ni++) acc[mi][ni] = (f32x4){0.f,0.f,0.f,0.f}; \
    } \
    _Pragma("unroll") \
    for (int s=0;s<2;s++){ \
      _Pragma("unroll") \
      for (int mi=0;mi<4;mi++){ \
        _Pragma("unroll") \
        for (int ni=0;ni<2;ni++){ \
          acc[mi][ni] = __builtin_amdgcn_mfma_f32_16x16x32_bf16(ah[mi][s], BH[ni][s], acc[mi][ni], 0,0,0); \
          acc[mi][ni] = __builtin_amdgcn_mfma_f32_16x16x32_bf16(ah[mi][s], BL[ni][s], acc[mi][ni], 0,0,0); \
          acc[mi][ni] = __builtin_amdgcn_mfma_f32_16x16x32_bf16(al[mi][s], BH[ni][s], acc[mi][ni], 0,0,0); \
        } \
      } \
    } \
    _Pragma("unroll") \
    for (int mi=0;mi<4;mi++){ \
      _Pragma("unroll") \
      for (int ni=0;ni<2;ni++){ \
        _Pragma("unroll") \
        for (int reg=0;reg<4;reg++) \
          sc[mi*16 + quad*4 + reg][w*32 + ni*16 + row16] = acc[mi][ni][reg]; \
      } \
    } \
    asm volatile("s_waitcnt lgkmcnt(0)" ::: "memory"); \
    for (int j=0;j<32;j++){ \
      float v = sc[lane][w*32 + j]; \
      float k = fabsf(v); \
      int ci = (IT)*128 + w*32 + j; \
      if (k > Tk || (k == Tk && ci < Ti)){ \
        int pos = 15; \
        while (pos > 0){ \
          float pv = topV[w][lane][pos-1]; \
          int   pi = topI[w][lane][pos-1]; \
          float pk = (pi==0x7fffffff) ? -1.f : fabsf(pv); \
          if (pk > k || (pk == k && pi < ci)) break; \
          topV[w][lane][pos] = pv; topI[w][lane][pos] = pi; \
          pos--; \
        } \
        topV[w][lane][pos] = v; topI[w][lane][pos] = ci; \
        int ti15 = topI[w][lane][15]; \
        Ti = ti15; \
        Tk = (ti15==0x7fffffff) ? -1.f : fabsf(topV[w][lane][15]); \
      } \
    } }

  // main loop over 32 slabs of 128 src cols, B-frags double-buffered
  bf16x8 bhA[2][2], blA[2][2], bhB[2][2], blB[2][2];
  LOADB(bhA, blA, 0);
  for (int it=0; it<32; it+=2){
    LOADB(bhB, blB, it+1);
    PROCESS(bhA, blA, it);
    if (it+2 < 32) LOADB(bhA, blA, it+2);
    PROCESS(bhB, blB, it+1);
  }
#undef LOADB
#undef PROCESS

  __syncthreads();
  // final 4-way merge of sorted partial lists: 4 lanes per row, head-ptr merge
  {
    int row = t>>2, s4 = t&3;
    long orow = ((long)b*NN + dst0 + row)*KK;
    int ptr = 0;
    for (int r=0;r<KK;r++){
      float hv = 0.f, hk = -1.f; int hi_ = 0x7fffffff;
      if (ptr < 16){
        hv = topV[s4][row][ptr];
        hi_ = topI[s4][row][ptr];
        hk = (hi_==0x7fffffff) ? -1.f : fabsf(hv);
      }
      float bk=hk, bv=hv; int bi=hi_;
      #pragma unroll
      for (int o=1;o<4;o<<=1){
        float ko=__shfl_xor(bk,o,64);
        int   io=__shfl_xor(bi,o,64);
        float vo=__shfl_xor(bv,o,64);
        if (ko>bk || (ko==bk && io<bi)){ bk=ko; bi=io; bv=vo; }
      }
      if (s4==0){ wout[orow+r]=bv; iout[orow+r]=bi; }
      if (bi == hi_) ptr++;
    }
  }
}

// ---- gather + signed-softmax weights + fused apply_delta ----
// v3: one WAVE per output row (4 rows/block), no LDS, no __syncthreads.
__global__ void __launch_bounds__(256) gather_kernel(
    const float* __restrict__ wbuf, const int* __restrict__ ibuf,
    const float* __restrict__ sv, long sv_bs,
    const float* __restrict__ nrm,
    const float* __restrict__ st, long st_bs,
    const float* __restrict__ base, int base_mod,
    const float* __restrict__ bg, const float* __restrict__ bb,
    const float* __restrict__ og, const float* __restrict__ ob,
    float* __restrict__ outv, float* __restrict__ ds)
{
  int t = threadIdx.x;
  int wid = t>>6, lane = t&63;
  long row = (long)blockIdx.x*4 + wid;
  int b = (int)(row >> 12);

  // ---- weights (all four 16-lane groups compute identical results) ----
  int kk = lane & 15;
  int si = ibuf[row*KK + kk];
  float w = wbuf[row*KK + kk];
  float aw = fabsf(w);
  float m = aw;
  #pragma unroll
  for (int o=1;o<16;o<<=1) m = fmaxf(m, __shfl_xor(m,o,64));
  float e = expf(aw - m);
  float Z = e;
  #pragma unroll
  for (int o=1;o<16;o<<=1) Z += __shfl_xor(Z,o,64);
  float sg = (w>0.f)?1.f:((w<0.f)?-1.f:0.f);
  float vv = sg*e/Z;
  if (st){
    float stv = st[(long)b*st_bs + si];
    vv *= fmaxf(stv,0.f) + log1pf(expf(-fabsf(stv)));   // softplus
  }
  float wsum = vv;
  #pragma unroll
  for (int o=1;o<16;o<<=1) wsum += __shfl_xor(wsum,o,64);
  if (lane==0) ds[row] = wsum;
  float wkp = vv * nrm[(long)b*NN + si];

  // ---- message accumulation: lane owns d = lane*4 .. lane*4+3 ----
  float4 acc = {0.f,0.f,0.f,0.f};
  const float* svb = sv + (long)b*sv_bs;
  #pragma unroll
  for (int k=0;k<KK;k++){
    int   sik = __shfl(si, k, 64);
    float wk  = __shfl(wkp, k, 64);
    float4 mq = *(const float4*)(svb + (long)sik*DD + lane*4);
    acc.x += wk*mq.x; acc.y += wk*mq.y; acc.z += wk*mq.z; acc.w += wk*mq.w;
  }

  if (!base){
    *(float4*)(outv + row*DD + lane*4) = acc;
    return;
  }
  const float* brow = base + (long)(base_mod ? (row % base_mod) : row)*DD;
  float4 x4 = *(const float4*)(brow + lane*4);
  if (bg){
    float s = x4.x+x4.y+x4.z+x4.w;
    float q = x4.x*x4.x+x4.y*x4.y+x4.z*x4.z+x4.w*x4.w;
    #pragma unroll
    for (int o=1;o<64;o<<=1){ s+=__shfl_xor(s,o,64); q+=__shfl_xor(q,o,64); }
    float mm=s*(1.f/DD), var=q*(1.f/DD)-mm*mm, rstd=rsqrtf(var+1e-5f);
    float4 g4 = *(const float4*)(bg + lane*4);
    float4 b4 = *(const float4*)(bb + lane*4);
    x4.x=(x4.x-mm)*rstd*g4.x+b4.x; x4.y=(x4.y-mm)*rstd*g4.y+b4.y;
    x4.z=(x4.z-mm)*rstd*g4.z+b4.z; x4.w=(x4.w-mm)*rstd*g4.w+b4.w;
  }
  x4.x+=acc.x; x4.y+=acc.y; x4.z+=acc.z; x4.w+=acc.w;
  {
    float s = x4.x+x4.y+x4.z+x4.w;
    float q = x4.x*x4.x+x4.y*x4.y+x4.z*x4.z+x4.w*x4.w;
    #pragma unroll
    for (int o=1;o<64;o<<=1){ s+=__shfl_xor(s,o,64); q+=__shfl_xor(q,o,64); }
    float mm=s*(1.f/DD), var=q*(1.f/DD)-mm*mm, rstd=rsqrtf(var+1e-5f);
    float4 g4 = *(const float4*)(og + lane*4);
    float4 b4 = *(const float4*)(ob + lane*4);
    float4 o4;
    o4.x=(x4.x-mm)*rstd*g4.x+b4.x; o4.y=(x4.y-mm)*rstd*g4.y+b4.y;
    o4.z=(x4.z-mm)*rstd*g4.z+b4.z; o4.w=(x4.w-mm)*rstd*g4.w+b4.w;
    *(float4*)(outv + row*DD + lane*4) = o4;
  }
}

extern "C" void kernel_launch(void* const* d_in, const int* in_sizes, int n_in,
                              void* d_out, int out_size, void* d_ws, size_t ws_size,
                              hipStream_t stream)
{
  const float* b_state    = (const float*)d_in[0];
  const float* b_val      = (const float*)d_in[1];
  const float* init_state = (const float*)d_in[2];
  const float* init_val   = (const float*)d_in[3];
  const float* U_bk = (const float*)d_in[4];
  const float* V_bk = (const float*)d_in[5];
  const float* U_kb = (const float*)d_in[6];
  const float* V_kb = (const float*)d_in[7];
  const float* U_p  = (const float*)d_in[8];
  const float* V_p  = (const float*)d_in[9];
  const float* kn_g = (const float*)d_in[10];
  const float* kn_b = (const float*)d_in[11];
  const float* bn_g = (const float*)d_in[12];
  const float* bn_b = (const float*)d_in[13];
  const float* pn_g = (const float*)d_in[14];
  const float* pn_b = (const float*)d_in[15];
  float* out = (float*)d_out;

  const long o_rstate = 0;
  const long o_rval   = (long)BB*NN;
  const long o_pstate = o_rval + (long)BB*NN*DD;
  const long o_pval   = o_pstate + (long)BB*NN;
  const long o_bds    = o_pval + (long)BB*NN*DD;
  const long o_bdv    = o_bds + (long)BB*NN;

  float* RVAL = out + o_rval;
  float* PVAL = out + o_pval;
  float* RST  = out + o_rstate;
  float* PST  = out + o_pstate;

  ushort* SPh = (ushort*)d_ws;                   // [B,N,R] bf16 hi
  ushort* SPl = SPh + (long)BB*NN*RR;
  ushort* DPh = SPl + (long)BB*NN*RR;
  ushort* DPl = DPh + (long)BB*NN*RR;
  float* WB   = (float*)(DPl + (long)BB*NN*RR);  // [B,N,K]
  int*   IB   = (int*)(WB + (long)BB*NN*KK);     // [B,N,K]
  float* KST  = (float*)(IB + (long)BB*NN*KK);   // [N]
  float* DS   = KST + NN;                        // [B,N]
  float* NV   = DS + (long)BB*NN;                // [B,N,D] normalized msgs
  float* NRM  = NV + (long)BB*NN*DD;             // [B,N] 1/(||row||+1e-6)

  // ---- initialize_state: k_state (batch-independent) ----
  ssm_kernel<<<1,1024,0,stream>>>(init_state, 0, nullptr, 0, KST, 0);

  // ---- route_from_b: B -> K ----
  proj_ln_kernel<<<NN/TM,256,0,stream>>>(init_val, kn_g, kn_b, 2,
                                         V_bk, DPh, DPl, 0.125f, nullptr, nullptr, nullptr, 0.f,
                                         nullptr, nullptr);
  proj_ln_kernel<<<BB*NN/TM,256,0,stream>>>(b_val, nullptr, nullptr, 0,
                                            U_bk, SPh, SPl, 1.0f, nullptr, nullptr, nullptr, 0.f,
                                            nullptr, NRM);
  score_topk<<<dim3(NN/64, BB), 256, 0, stream>>>(DPh, DPl, 0, SPh, SPl, WB, IB);
  gather_kernel<<<BB*NN/4,256,0,stream>>>(WB, IB,
      b_val, (long)NN*DD, NRM,
      b_state, (long)NN,
      init_val, NN, kn_g, kn_b, kn_g, kn_b,
      RVAL, DS);
  ssm_kernel<<<BB,1024,0,stream>>>(KST, 0, DS, NN, RST, NN);

  // ---- propagate ----
  proj_ln_kernel<<<BB*NN/TM,256,0,stream>>>(RVAL, pn_g, pn_b, 1,
                                            U_p, SPh, SPl, 1.0f, V_p, DPh, DPl, 0.125f,
                                            NV, NRM);
  score_topk<<<dim3(NN/64, BB), 256, 0, stream>>>(DPh, DPl, (long)NN*RR, SPh, SPl, WB, IB);
  gather_kernel<<<BB*NN/4,256,0,stream>>>(WB, IB,
      NV, (long)NN*DD, NRM,
      nullptr, 0,
      RVAL, 0, nullptr, nullptr, kn_g, kn_b,
      PVAL, DS);
  ssm_kernel<<<BB,1024,0,stream>>>(RST, NN, DS, NN, PST, NN);

  // ---- transition_to_b: K -> B ----
  proj_ln_kernel<<<BB*NN/TM,256,0,stream>>>(PVAL, kn_g, kn_b, 1,
                                            U_kb, SPh, SPl, 1.0f, nullptr, nullptr, nullptr, 0.f,
                                            NV, NRM);
  proj_ln_kernel<<<BB*NN/TM,256,0,stream>>>(b_val, bn_g, bn_b, 1,
                                            V_kb, DPh, DPl, 0.125f, nullptr, nullptr, nullptr, 0.f,
                                            nullptr, nullptr);
  score_topk<<<dim3(NN/64, BB), 256, 0, stream>>>(DPh, DPl, (long)NN*RR, SPh, SPl, WB, IB);
  gather_kernel<<<BB*NN/4,256,0,stream>>>(WB, IB,
      NV, (long)NN*DD, NRM,
      PST, (long)NN,
      nullptr, 0, nullptr, nullptr, nullptr, nullptr,
      out + o_bdv, out + o_bds);
}

// Round 4
// 1299.751 us; speedup vs baseline: 4.1181x; 4.1181x over previous
//
#include <hip/hip_runtime.h>
#include <hip/hip_bf16.h>

#define BB 4
#define NN 4096
#define DD 256
#define RR 64
#define KK 16
#define TM 16   // rows per projection block

typedef __attribute__((ext_vector_type(8))) short bf16x8;
typedef __attribute__((ext_vector_type(4))) float f32x4;

__device__ __forceinline__ void f32_split(float x, ushort* h, ushort* l){
  __hip_bfloat16 hb = __float2bfloat16(x);
  float hf = __bfloat162float(hb);
  __hip_bfloat16 lb = __float2bfloat16(x - hf);
  *h = *(ushort*)&hb; *l = *(ushort*)&lb;
}

__device__ __forceinline__ float bf2f(ushort u){
  unsigned x = ((unsigned)u)<<16; return __builtin_bit_cast(float, x);
}

// ---------------- signed softmax over 4096 (block per row, 1024 thr) ----------------
__global__ void __launch_bounds__(1024) ssm_kernel(
    const float* __restrict__ xf, long xf_stride,
    const float* __restrict__ add, long add_stride,
    float* __restrict__ outf, long outf_stride)
{
  __shared__ float sm[32];
  int t = threadIdx.x;
  long b = blockIdx.x;
  float x[4]; float mx = 0.f;
  #pragma unroll
  for (int j=0;j<4;j++){
    int i = t + j*1024;
    float v = xf[b*xf_stride + i];
    if (add) v += add[b*add_stride + i];
    x[j]=v; mx = fmaxf(mx, fabsf(v));
  }
  #pragma unroll
  for (int o=1;o<64;o<<=1) mx = fmaxf(mx, __shfl_xor(mx,o,64));
  int wid = t>>6;
  if ((t&63)==0) sm[wid]=mx;
  __syncthreads();
  mx = sm[0];
  #pragma unroll
  for (int w=1;w<16;w++) mx = fmaxf(mx, sm[w]);
  float e[4]; float ssum=0.f;
  #pragma unroll
  for (int j=0;j<4;j++){ e[j]=expf(fabsf(x[j])-mx); ssum+=e[j]; }
  #pragma unroll
  for (int o=1;o<64;o<<=1) ssum += __shfl_xor(ssum,o,64);
  if ((t&63)==0) sm[16+wid]=ssum;
  __syncthreads();
  ssum = sm[16];
  #pragma unroll
  for (int w=1;w<16;w++) ssum += sm[16+w];
  float inv = 1.0f/ssum;
  #pragma unroll
  for (int j=0;j<4;j++){
    int i = t + j*1024;
    float sg = (x[j]>0.f)?1.f:((x[j]<0.f)?-1.f:0.f);
    outf[b*outf_stride + i] = sg*e[j]*inv;
  }
}

// ------ projection with 0/1/2 inline layernorms: out = ln^nln(src) @ [U|V] ------
__global__ void __launch_bounds__(256) proj_ln_kernel(
    const float* __restrict__ src,
    const float* __restrict__ lg, const float* __restrict__ lb, int nln,
    const float* __restrict__ U, ushort* __restrict__ oUh, ushort* __restrict__ oUl, float scaleU,
    const float* __restrict__ V, ushort* __restrict__ oVh, ushort* __restrict__ oVl, float scaleV,
    float* __restrict__ nvout, float* __restrict__ nrmout)
{
  __shared__ float xs[TM][DD];     // 16 KB
  __shared__ float ut[64*64];      // 16 KB
  __shared__ float vt[64*64];      // 16 KB
  int t = threadIdx.x;
  int wid = t>>6, lane = t&63;
  long row0 = (long)blockIdx.x*TM;

  float gv[4], bv[4];
  if (nln){
    #pragma unroll
    for (int u=0;u<4;u++){ int d=u*64+lane; gv[u]=lg[d]; bv[u]=lb[d]; }
  }
  for (int rr=0; rr<4; rr++){
    int r = wid*4 + rr;
    const float* srow = src + (row0 + r)*DD;
    float x[4];
    #pragma unroll
    for (int u=0;u<4;u++) x[u] = srow[u*64 + lane];
    for (int p=0;p<nln;p++){
      float s=0.f,q=0.f;
      #pragma unroll
      for (int u=0;u<4;u++){ s+=x[u]; q+=x[u]*x[u]; }
      #pragma unroll
      for (int o=1;o<64;o<<=1){ s+=__shfl_xor(s,o,64); q+=__shfl_xor(q,o,64); }
      float m = s*(1.f/DD), var = q*(1.f/DD)-m*m, rstd = rsqrtf(var+1e-5f);
      #pragma unroll
      for (int u=0;u<4;u++) x[u] = (x[u]-m)*rstd*gv[u]+bv[u];
    }
    if (nrmout){
      float ss=0.f;
      #pragma unroll
      for (int u=0;u<4;u++) ss += x[u]*x[u];
      #pragma unroll
      for (int o=1;o<64;o<<=1) ss += __shfl_xor(ss,o,64);
      if (lane==0) nrmout[row0 + r] = 1.f/(sqrtf(ss)+1e-6f);
    }
    if (nvout){
      #pragma unroll
      for (int u=0;u<4;u++) nvout[(row0 + r)*DD + u*64 + lane] = x[u];
    }
    #pragma unroll
    for (int u=0;u<4;u++) xs[r][u*64+lane] = x[u];
  }
  __syncthreads();

  float aU[4] = {0.f,0.f,0.f,0.f};
  float aV[4] = {0.f,0.f,0.f,0.f};
  for (int kt=0; kt<4; kt++){
    const float4* Ut = (const float4*)(U + (long)kt*64*RR);
    #pragma unroll
    for (int i=0;i<4;i++) ((float4*)ut)[i*256 + t] = Ut[i*256 + t];
    if (V){
      const float4* Vt = (const float4*)(V + (long)kt*64*RR);
      #pragma unroll
      for (int i=0;i<4;i++) ((float4*)vt)[i*256 + t] = Vt[i*256 + t];
    }
    __syncthreads();
    #pragma unroll 4
    for (int dd=0; dd<64; dd+=4){
      float4 xq[4];
      #pragma unroll
      for (int r=0;r<4;r++) xq[r] = *(const float4*)&xs[wid*4+r][kt*64+dd];
      #pragma unroll
      for (int j=0;j<4;j++){
        float uv = ut[(dd+j)*64 + lane];
        float vv = V ? vt[(dd+j)*64 + lane] : 0.f;
        #pragma unroll
        for (int r=0;r<4;r++){
          float xv = (j==0)?xq[r].x:(j==1)?xq[r].y:(j==2)?xq[r].z:xq[r].w;
          aU[r] += xv*uv;
          if (V) aV[r] += xv*vv;
        }
      }
    }
    __syncthreads();
  }
  #pragma unroll
  for (int r=0;r<4;r++){
    long row = row0 + wid*4 + r;
    ushort h, l;
    f32_split(aU[r]*scaleU, &h, &l);
    oUh[row*RR + lane] = h; oUl[row*RR + lane] = l;
    if (V){
      f32_split(aV[r]*scaleV, &h, &l);
      oVh[row*RR + lane] = h; oVl[row*RR + lane] = l;
    }
  }
}

// ======================= two-sweep fused score/top-k =======================
// Swapped-operand MFMA: A = src proj (sp), B = dst proj (dp).
// D[i=src][j=dst]; lane (quad,r16) holds 4 src scores (reg r) for dst r16.
// Sweep A: per-lane register partial maxes -> PM[B][N][64] (4 splits x quad x reg).
// tsel:    T[row] = 16th-largest of 64 partials (provable lower bound on the
//          true 16th |value|: the 16 extracted partials are 16 distinct values
//          >= T).  Also zeroes CNT for the collect pass.
// Sweep B: same GEMM, filter |v| >= T, append (v,src) via atomicAdd into a
//          128-cap per-row list.
// sel16:   <=128 candidates -> exact (|v| desc, idx asc) extraction (verbatim
//          round-1 fast path); >128 (degenerate) -> exact GEMV re-scan.

#define SPLITS 4
#define STEPS  (NN/SPLITS/16)   // 64
#define CCAP   128

#define LOADA(AH0,AH1,AL0,AL1, STEP) { \
    const ushort* p_ = Sh + (long)(STEP)*16*RR; \
    const ushort* q_ = Sl + (long)(STEP)*16*RR; \
    AH0 = *(const bf16x8*)(p_);      AH1 = *(const bf16x8*)(p_ + 32); \
    AL0 = *(const bf16x8*)(q_);      AL1 = *(const bf16x8*)(q_ + 32); }

#define MFMA6(AH0,AH1,AL0,AL1, ACC) { \
    ACC = __builtin_amdgcn_mfma_f32_16x16x32_bf16(AH0, dh0, ACC, 0,0,0); \
    ACC = __builtin_amdgcn_mfma_f32_16x16x32_bf16(AL0, dh0, ACC, 0,0,0); \
    ACC = __builtin_amdgcn_mfma_f32_16x16x32_bf16(AH0, dl0, ACC, 0,0,0); \
    ACC = __builtin_amdgcn_mfma_f32_16x16x32_bf16(AH1, dh1, ACC, 0,0,0); \
    ACC = __builtin_amdgcn_mfma_f32_16x16x32_bf16(AL1, dh1, ACC, 0,0,0); \
    ACC = __builtin_amdgcn_mfma_f32_16x16x32_bf16(AH1, dl1, ACC, 0,0,0); }

__global__ void __launch_bounds__(256) score_max(
    const ushort* __restrict__ dph, const ushort* __restrict__ dpl, long dp_bs,
    const ushort* __restrict__ sph, const ushort* __restrict__ spl,
    float* __restrict__ PM)
{
  const int b = blockIdx.z, split = blockIdx.y;
  const int t = threadIdx.x;
  const int w = t>>6, lane = t&63;
  const int r16 = lane&15, quad = lane>>4;
  const int dst = blockIdx.x*64 + w*16 + r16;
  const int src0 = split*(NN/SPLITS);

  const ushort* Dh = dph + (long)b*dp_bs + (long)dst*RR + quad*8;
  const ushort* Dl = dpl + (long)b*dp_bs + (long)dst*RR + quad*8;
  bf16x8 dh0 = *(const bf16x8*)(Dh);
  bf16x8 dh1 = *(const bf16x8*)(Dh + 32);
  bf16x8 dl0 = *(const bf16x8*)(Dl);
  bf16x8 dl1 = *(const bf16x8*)(Dl + 32);

  const ushort* Sh = sph + (long)b*NN*RR + (long)(src0 + r16)*RR + quad*8;
  const ushort* Sl = spl + (long)b*NN*RR + (long)(src0 + r16)*RR + quad*8;

  float pm0=0.f, pm1=0.f, pm2=0.f, pm3=0.f;
  bf16x8 xh0,xh1,xl0,xl1, yh0,yh1,yl0,yl1;
  LOADA(xh0,xh1,xl0,xl1, 0)
  for (int st=0; st<STEPS; st+=2){
    LOADA(yh0,yh1,yl0,yl1, st+1)
    {
      f32x4 acc = (f32x4){0.f,0.f,0.f,0.f};
      MFMA6(xh0,xh1,xl0,xl1, acc)
      pm0 = fmaxf(pm0, fabsf(acc[0])); pm1 = fmaxf(pm1, fabsf(acc[1]));
      pm2 = fmaxf(pm2, fabsf(acc[2])); pm3 = fmaxf(pm3, fabsf(acc[3]));
    }
    if (st+2 < STEPS) LOADA(xh0,xh1,xl0,xl1, st+2)
    {
      f32x4 acc = (f32x4){0.f,0.f,0.f,0.f};
      MFMA6(yh0,yh1,yl0,yl1, acc)
      pm0 = fmaxf(pm0, fabsf(acc[0])); pm1 = fmaxf(pm1, fabsf(acc[1]));
      pm2 = fmaxf(pm2, fabsf(acc[2])); pm3 = fmaxf(pm3, fabsf(acc[3]));
    }
  }
  float* pmr = PM + ((long)b*NN + dst)*64 + split*16 + quad*4;
  pmr[0]=pm0; pmr[1]=pm1; pmr[2]=pm2; pmr[3]=pm3;
}

// T[row] = 16th-largest of the 64 partial maxes; zero CNT for collect pass
__global__ void __launch_bounds__(256) tsel_kernel(
    const float* __restrict__ PM, float* __restrict__ T, int* __restrict__ CNT)
{
  int wid = threadIdx.x>>6, lane = threadIdx.x&63;
  long g = (long)blockIdx.x*4 + wid;
  float cur = PM[g*64 + lane];
  float Tv = 0.f;
  for (int t=0;t<16;t++){
    float m = cur;
    #pragma unroll
    for (int o=1;o<64;o<<=1) m = fmaxf(m, __shfl_xor(m,o,64));
    Tv = m;
    unsigned long long msk = __ballot(cur == m);
    int low = __ffsll(msk) - 1;
    if (lane == low) cur = -1.f;
  }
  if (lane==0){ T[g] = Tv; CNT[g] = 0; }
}

__global__ void __launch_bounds__(256) score_collect(
    const ushort* __restrict__ dph, const ushort* __restrict__ dpl, long dp_bs,
    const ushort* __restrict__ sph, const ushort* __restrict__ spl,
    const float* __restrict__ T, int* __restrict__ CNT,
    float* __restrict__ CV, int* __restrict__ CI)
{
  const int b = blockIdx.z, split = blockIdx.y;
  const int t = threadIdx.x;
  const int w = t>>6, lane = t&63;
  const int r16 = lane&15, quad = lane>>4;
  const int dst = blockIdx.x*64 + w*16 + r16;
  const int src0 = split*(NN/SPLITS);
  const long row = (long)b*NN + dst;

  const ushort* Dh = dph + (long)b*dp_bs + (long)dst*RR + quad*8;
  const ushort* Dl = dpl + (long)b*dp_bs + (long)dst*RR + quad*8;
  bf16x8 dh0 = *(const bf16x8*)(Dh);
  bf16x8 dh1 = *(const bf16x8*)(Dh + 32);
  bf16x8 dl0 = *(const bf16x8*)(Dl);
  bf16x8 dl1 = *(const bf16x8*)(Dl + 32);

  const ushort* Sh = sph + (long)b*NN*RR + (long)(src0 + r16)*RR + quad*8;
  const ushort* Sl = spl + (long)b*NN*RR + (long)(src0 + r16)*RR + quad*8;

  const float Trow = T[row];
  int* cntp = CNT + row;
  float* cvp = CV + row*CCAP;
  int*   cip = CI + row*CCAP;

#define COLLECT(ACC, STEP) { \
    float m01 = fmaxf(fabsf(ACC[0]), fabsf(ACC[1])); \
    float m23 = fmaxf(fabsf(ACC[2]), fabsf(ACC[3])); \
    if (fmaxf(m01,m23) >= Trow){ \
      int sbase = src0 + (STEP)*16 + quad*4; \
      _Pragma("unroll") \
      for (int r=0;r<4;r++){ \
        if (fabsf(ACC[r]) >= Trow){ \
          int slot = atomicAdd(cntp, 1); \
          if (slot < CCAP){ cvp[slot] = ACC[r]; cip[slot] = sbase + r; } \
        } \
      } \
    } }

  bf16x8 xh0,xh1,xl0,xl1, yh0,yh1,yl0,yl1;
  LOADA(xh0,xh1,xl0,xl1, 0)
  for (int st=0; st<STEPS; st+=2){
    LOADA(yh0,yh1,yl0,yl1, st+1)
    {
      f32x4 acc = (f32x4){0.f,0.f,0.f,0.f};
      MFMA6(xh0,xh1,xl0,xl1, acc)
      COLLECT(acc, st)
    }
    if (st+2 < STEPS) LOADA(xh0,xh1,xl0,xl1, st+2)
    {
      f32x4 acc = (f32x4){0.f,0.f,0.f,0.f};
      MFMA6(yh0,yh1,yl0,yl1, acc)
      COLLECT(acc, st+1)
    }
  }
#undef COLLECT
}

// final exact top-16 per row from the candidate list (or GEMV fallback)
__global__ void __launch_bounds__(256) sel16_kernel(
    const float* __restrict__ CV, const int* __restrict__ CI, const int* __restrict__ CNT,
    const ushort* __restrict__ dph, const ushort* __restrict__ dpl, long dp_bs,
    const ushort* __restrict__ sph, const ushort* __restrict__ spl,
    float* __restrict__ wout, int* __restrict__ iout)
{
  int wid = threadIdx.x>>6, lane = threadIdx.x&63;
  long g = (long)blockIdx.x*4 + wid;
  int b = (int)(g >> 12);
  int n = (int)(g & (NN-1));
  int C = CNT[g];
  long orow = g*KK;
  if (C <= CCAP){
    const float* cvp = CV + g*CCAP;
    const int*   cip = CI + g*CCAP;
    float cv0 = 0.f, cv1 = 0.f; int ci0 = 0x7fffffff, ci1 = 0x7fffffff;
    if (lane < C){ cv0 = cvp[lane]; ci0 = cip[lane]; }
    if (lane+64 < C){ cv1 = cvp[lane+64]; ci1 = cip[lane+64]; }
    float k0=fabsf(cv0), k1=fabsf(cv1);
    bool f0=(ci0==0x7fffffff), f1=(ci1==0x7fffffff);
    for (int t=0;t<KK;t++){
      float bk; int bgi; float bv;
      bool pick0 = !f0 && (f1 || k0>k1 || (k0==k1 && ci0<ci1));
      if (pick0){ bk=k0; bgi=ci0; bv=cv0; }
      else if (!f1){ bk=k1; bgi=ci1; bv=cv1; }
      else { bk=-1.f; bgi=0x7fffffff; bv=0.f; }
      #pragma unroll
      for (int o=1;o<64;o<<=1){
        float ko=__shfl_xor(bk,o,64);
        int  gio=__shfl_xor(bgi,o,64);
        float vo=__shfl_xor(bv,o,64);
        if (ko>bk || (ko==bk && gio<bgi)){ bk=ko; bgi=gio; bv=vo; }
      }
      if (lane==0){ wout[orow+t]=bv; iout[orow+t]=bgi; }
      if (!f0 && bgi==ci0) f0=true;
      else if (!f1 && bgi==ci1) f1=true;
    }
  } else {
    // degenerate row: exact re-scan (recompute scores from hi+lo projections)
    const ushort* dh = dph + (long)b*dp_bs + (long)n*RR;
    const ushort* dl = dpl + (long)b*dp_bs + (long)n*RR;
    const ushort* shb = sph + (long)b*NN*RR;
    const ushort* slb = spl + (long)b*NN*RR;
    float v[64];
    for (int j=0;j<64;j++){
      int src = lane*64 + j;
      const ushort* sh = shb + (long)src*RR;
      const ushort* sl = slb + (long)src*RR;
      float acc = 0.f;
      for (int k=0;k<RR;k++){
        float d = bf2f(dh[k]) + bf2f(dl[k]);
        float s = bf2f(sh[k]) + bf2f(sl[k]);
        acc += d*s;
      }
      v[j] = acc;
    }
    unsigned long long cons = 0ull;
    float bk=-1.f, bval=0.f; int bj=0;
    #pragma unroll
    for (int j=0;j<64;j++){
      float k = fabsf(v[j]);
      if (k > bk){ bk=k; bj=j; bval=v[j]; }
    }
    for (int t=0;t<KK;t++){
      float k = bk; int gi = lane*64 + bj; float val = bval;
      #pragma unroll
      for (int o=1;o<64;o<<=1){
        float ko = __shfl_xor(k,o,64);
        int  gio = __shfl_xor(gi,o,64);
        float vo = __shfl_xor(val,o,64);
        if (ko > k || (ko == k && gio < gi)){ k=ko; gi=gio; val=vo; }
      }
      if (lane == 0){ wout[orow+t]=val; iout[orow+t]=gi; }
      if (lane == (gi>>6)){
        cons |= 1ull << (gi & 63);
        bk=-1.f; bj=0; bval=0.f;
        #pragma unroll
        for (int j=0;j<64;j++){
          if (!((cons>>j)&1ull)){
            float kk=fabsf(v[j]);
            if (kk>bk){ bk=kk; bj=j; bval=v[j]; }
          }
        }
      }
    }
  }
}

// ---- gather + signed-softmax weights + fused apply_delta (wave per row) ----
__global__ void __launch_bounds__(256) gather_kernel(
    const float* __restrict__ wbuf, const int* __restrict__ ibuf,
    const float* __restrict__ sv, long sv_bs,
    const float* __restrict__ nrm,
    const float* __restrict__ st, long st_bs,
    const float* __restrict__ base, int base_mod,
    const float* __restrict__ bg, const float* __restrict__ bb,
    const float* __restrict__ og, const float* __restrict__ ob,
    float* __restrict__ outv, float* __restrict__ ds)
{
  int t = threadIdx.x;
  int wid = t>>6, lane = t&63;
  long row = (long)blockIdx.x*4 + wid;
  int b = (int)(row >> 12);

  int kk = lane & 15;
  int si = ibuf[row*KK + kk];
  float w = wbuf[row*KK + kk];
  float aw = fabsf(w);
  float m = aw;
  #pragma unroll
  for (int o=1;o<16;o<<=1) m = fmaxf(m, __shfl_xor(m,o,64));
  float e = expf(aw - m);
  float Z = e;
  #pragma unroll
  for (int o=1;o<16;o<<=1) Z += __shfl_xor(Z,o,64);
  float sg = (w>0.f)?1.f:((w<0.f)?-1.f:0.f);
  float vv = sg*e/Z;
  if (st){
    float stv = st[(long)b*st_bs + si];
    vv *= fmaxf(stv,0.f) + log1pf(expf(-fabsf(stv)));   // softplus
  }
  float wsum = vv;
  #pragma unroll
  for (int o=1;o<16;o<<=1) wsum += __shfl_xor(wsum,o,64);
  if (lane==0) ds[row] = wsum;
  float wkp = vv * nrm[(long)b*NN + si];

  float4 acc = {0.f,0.f,0.f,0.f};
  const float* svb = sv + (long)b*sv_bs;
  #pragma unroll
  for (int k=0;k<KK;k++){
    int   sik = __shfl(si, k, 64);
    float wk  = __shfl(wkp, k, 64);
    float4 mq = *(const float4*)(svb + (long)sik*DD + lane*4);
    acc.x += wk*mq.x; acc.y += wk*mq.y; acc.z += wk*mq.z; acc.w += wk*mq.w;
  }

  if (!base){
    *(float4*)(outv + row*DD + lane*4) = acc;
    return;
  }
  const float* brow = base + (long)(base_mod ? (row % base_mod) : row)*DD;
  float4 x4 = *(const float4*)(brow + lane*4);
  if (bg){
    float s = x4.x+x4.y+x4.z+x4.w;
    float q = x4.x*x4.x+x4.y*x4.y+x4.z*x4.z+x4.w*x4.w;
    #pragma unroll
    for (int o=1;o<64;o<<=1){ s+=__shfl_xor(s,o,64); q+=__shfl_xor(q,o,64); }
    float mm=s*(1.f/DD), var=q*(1.f/DD)-mm*mm, rstd=rsqrtf(var+1e-5f);
    float4 g4 = *(const float4*)(bg + lane*4);
    float4 b4 = *(const float4*)(bb + lane*4);
    x4.x=(x4.x-mm)*rstd*g4.x+b4.x; x4.y=(x4.y-mm)*rstd*g4.y+b4.y;
    x4.z=(x4.z-mm)*rstd*g4.z+b4.z; x4.w=(x4.w-mm)*rstd*g4.w+b4.w;
  }
  x4.x+=acc.x; x4.y+=acc.y; x4.z+=acc.z; x4.w+=acc.w;
  {
    float s = x4.x+x4.y+x4.z+x4.w;
    float q = x4.x*x4.x+x4.y*x4.y+x4.z*x4.z+x4.w*x4.w;
    #pragma unroll
    for (int o=1;o<64;o<<=1){ s+=__shfl_xor(s,o,64); q+=__shfl_xor(q,o,64); }
    float mm=s*(1.f/DD), var=q*(1.f/DD)-mm*mm, rstd=rsqrtf(var+1e-5f);
    float4 g4 = *(const float4*)(og + lane*4);
    float4 b4 = *(const float4*)(ob + lane*4);
    float4 o4;
    o4.x=(x4.x-mm)*rstd*g4.x+b4.x; o4.y=(x4.y-mm)*rstd*g4.y+b4.y;
    o4.z=(x4.z-mm)*rstd*g4.z+b4.z; o4.w=(x4.w-mm)*rstd*g4.w+b4.w;
    *(float4*)(outv + row*DD + lane*4) = o4;
  }
}

extern "C" void kernel_launch(void* const* d_in, const int* in_sizes, int n_in,
                              void* d_out, int out_size, void* d_ws, size_t ws_size,
                              hipStream_t stream)
{
  const float* b_state    = (const float*)d_in[0];
  const float* b_val      = (const float*)d_in[1];
  const float* init_state = (const float*)d_in[2];
  const float* init_val   = (const float*)d_in[3];
  const float* U_bk = (const float*)d_in[4];
  const float* V_bk = (const float*)d_in[5];
  const float* U_kb = (const float*)d_in[6];
  const float* V_kb = (const float*)d_in[7];
  const float* U_p  = (const float*)d_in[8];
  const float* V_p  = (const float*)d_in[9];
  const float* kn_g = (const float*)d_in[10];
  const float* kn_b = (const float*)d_in[11];
  const float* bn_g = (const float*)d_in[12];
  const float* bn_b = (const float*)d_in[13];
  const float* pn_g = (const float*)d_in[14];
  const float* pn_b = (const float*)d_in[15];
  float* out = (float*)d_out;

  const long o_rstate = 0;
  const long o_rval   = (long)BB*NN;
  const long o_pstate = o_rval + (long)BB*NN*DD;
  const long o_pval   = o_pstate + (long)BB*NN;
  const long o_bds    = o_pval + (long)BB*NN*DD;
  const long o_bdv    = o_bds + (long)BB*NN;

  float* RVAL = out + o_rval;
  float* PVAL = out + o_pval;
  float* RST  = out + o_rstate;
  float* PST  = out + o_pstate;

  ushort* SPh = (ushort*)d_ws;                   // [B,N,R] bf16 hi
  ushort* SPl = SPh + (long)BB*NN*RR;
  ushort* DPh = SPl + (long)BB*NN*RR;
  ushort* DPl = DPh + (long)BB*NN*RR;
  float* WB   = (float*)(DPl + (long)BB*NN*RR);  // [B,N,K]
  int*   IB   = (int*)(WB + (long)BB*NN*KK);     // [B,N,K]
  float* KST  = (float*)(IB + (long)BB*NN*KK);   // [N]
  float* DS   = KST + NN;                        // [B,N]
  float* NV   = DS + (long)BB*NN;                // [B,N,D] normalized msgs
  float* NRM  = NV + (long)BB*NN*DD;             // [B,N] 1/(||row||+1e-6)
  float* PM   = NRM + (long)BB*NN;               // [B,N,64] partial maxes
  float* TT   = PM + (long)BB*NN*64;             // [B,N] thresholds
  int*   CNT  = (int*)(TT + (long)BB*NN);        // [B,N] candidate counts
  float* CV   = (float*)(CNT + (long)BB*NN);     // [B,N,128] candidate values
  int*   CI   = (int*)(CV + (long)BB*NN*CCAP);   // [B,N,128] candidate indices

  auto run_scores = [&](long dpbs){
    score_max<<<dim3(NN/64, SPLITS, BB), 256, 0, stream>>>(DPh, DPl, dpbs, SPh, SPl, PM);
    tsel_kernel<<<BB*NN/4, 256, 0, stream>>>(PM, TT, CNT);
    score_collect<<<dim3(NN/64, SPLITS, BB), 256, 0, stream>>>(DPh, DPl, dpbs, SPh, SPl, TT, CNT, CV, CI);
    sel16_kernel<<<BB*NN/4, 256, 0, stream>>>(CV, CI, CNT, DPh, DPl, dpbs, SPh, SPl, WB, IB);
  };

  // ---- initialize_state: k_state (batch-independent) ----
  ssm_kernel<<<1,1024,0,stream>>>(init_state, 0, nullptr, 0, KST, 0);

  // ---- route_from_b: B -> K ----
  proj_ln_kernel<<<NN/TM,256,0,stream>>>(init_val, kn_g, kn_b, 2,
                                         V_bk, DPh, DPl, 0.125f, nullptr, nullptr, nullptr, 0.f,
                                         nullptr, nullptr);
  proj_ln_kernel<<<BB*NN/TM,256,0,stream>>>(b_val, nullptr, nullptr, 0,
                                            U_bk, SPh, SPl, 1.0f, nullptr, nullptr, nullptr, 0.f,
                                            nullptr, NRM);
  run_scores(0);
  gather_kernel<<<BB*NN/4,256,0,stream>>>(WB, IB,
      b_val, (long)NN*DD, NRM,
      b_state, (long)NN,
      init_val, NN, kn_g, kn_b, kn_g, kn_b,
      RVAL, DS);
  ssm_kernel<<<BB,1024,0,stream>>>(KST, 0, DS, NN, RST, NN);

  // ---- propagate ----
  proj_ln_kernel<<<BB*NN/TM,256,0,stream>>>(RVAL, pn_g, pn_b, 1,
                                            U_p, SPh, SPl, 1.0f, V_p, DPh, DPl, 0.125f,
                                            NV, NRM);
  run_scores((long)NN*RR);
  gather_kernel<<<BB*NN/4,256,0,stream>>>(WB, IB,
      NV, (long)NN*DD, NRM,
      nullptr, 0,
      RVAL, 0, nullptr, nullptr, kn_g, kn_b,
      PVAL, DS);
  ssm_kernel<<<BB,1024,0,stream>>>(RST, NN, DS, NN, PST, NN);

  // ---- transition_to_b: K -> B ----
  proj_ln_kernel<<<BB*NN/TM,256,0,stream>>>(PVAL, kn_g, kn_b, 1,
                                            U_kb, SPh, SPl, 1.0f, nullptr, nullptr, nullptr, 0.f,
                                            NV, NRM);
  proj_ln_kernel<<<BB*NN/TM,256,0,stream>>>(b_val, bn_g, bn_b, 1,
                                            V_kb, DPh, DPl, 0.125f, nullptr, nullptr, nullptr, 0.f,
                                            nullptr, nullptr);
  run_scores((long)NN*RR);
  gather_kernel<<<BB*NN/4,256,0,stream>>>(WB, IB,
      NV, (long)NN*DD, NRM,
      PST, (long)NN,
      nullptr, 0, nullptr, nullptr, nullptr, nullptr,
      out + o_bdv, out + o_bds);
}

// Round 5
// 994.015 us; speedup vs baseline: 5.3847x; 1.3076x over previous
//
#include <hip/hip_runtime.h>
#include <hip/hip_bf16.h>

#define BB 4
#define NN 4096
#define DD 256
#define RR 64
#define KK 16
#define TM 16   // rows per projection block

typedef __attribute__((ext_vector_type(8))) short bf16x8;
typedef __attribute__((ext_vector_type(4))) float f32x4;

__device__ __forceinline__ void f32_split(float x, ushort* h, ushort* l){
  __hip_bfloat16 hb = __float2bfloat16(x);
  float hf = __bfloat162float(hb);
  __hip_bfloat16 lb = __float2bfloat16(x - hf);
  *h = *(ushort*)&hb; *l = *(ushort*)&lb;
}

__device__ __forceinline__ float bf2f(ushort u){
  unsigned x = ((unsigned)u)<<16; return __builtin_bit_cast(float, x);
}

// ---------------- signed softmax over 4096 (block per row, 1024 thr) ----------------
__global__ void __launch_bounds__(1024) ssm_kernel(
    const float* __restrict__ xf, long xf_stride,
    const float* __restrict__ add, long add_stride,
    float* __restrict__ outf, long outf_stride)
{
  __shared__ float sm[32];
  int t = threadIdx.x;
  long b = blockIdx.x;
  float x[4]; float mx = 0.f;
  #pragma unroll
  for (int j=0;j<4;j++){
    int i = t + j*1024;
    float v = xf[b*xf_stride + i];
    if (add) v += add[b*add_stride + i];
    x[j]=v; mx = fmaxf(mx, fabsf(v));
  }
  #pragma unroll
  for (int o=1;o<64;o<<=1) mx = fmaxf(mx, __shfl_xor(mx,o,64));
  int wid = t>>6;
  if ((t&63)==0) sm[wid]=mx;
  __syncthreads();
  mx = sm[0];
  #pragma unroll
  for (int w=1;w<16;w++) mx = fmaxf(mx, sm[w]);
  float e[4]; float ssum=0.f;
  #pragma unroll
  for (int j=0;j<4;j++){ e[j]=expf(fabsf(x[j])-mx); ssum+=e[j]; }
  #pragma unroll
  for (int o=1;o<64;o<<=1) ssum += __shfl_xor(ssum,o,64);
  if ((t&63)==0) sm[16+wid]=ssum;
  __syncthreads();
  ssum = sm[16];
  #pragma unroll
  for (int w=1;w<16;w++) ssum += sm[16+w];
  float inv = 1.0f/ssum;
  #pragma unroll
  for (int j=0;j<4;j++){
    int i = t + j*1024;
    float sg = (x[j]>0.f)?1.f:((x[j]<0.f)?-1.f:0.f);
    outf[b*outf_stride + i] = sg*e[j]*inv;
  }
}

// ------ projection with 0/1/2 inline layernorms: out = ln^nln(src) @ [U|V] ------
__global__ void __launch_bounds__(256) proj_ln_kernel(
    const float* __restrict__ src,
    const float* __restrict__ lg, const float* __restrict__ lb, int nln,
    const float* __restrict__ U, ushort* __restrict__ oUh, ushort* __restrict__ oUl, float scaleU,
    const float* __restrict__ V, ushort* __restrict__ oVh, ushort* __restrict__ oVl, float scaleV,
    float* __restrict__ nvout, float* __restrict__ nrmout)
{
  __shared__ float xs[TM][DD];     // 16 KB
  __shared__ float ut[64*64];      // 16 KB
  __shared__ float vt[64*64];      // 16 KB
  int t = threadIdx.x;
  int wid = t>>6, lane = t&63;
  long row0 = (long)blockIdx.x*TM;

  float gv[4], bv[4];
  if (nln){
    #pragma unroll
    for (int u=0;u<4;u++){ int d=u*64+lane; gv[u]=lg[d]; bv[u]=lb[d]; }
  }
  for (int rr=0; rr<4; rr++){
    int r = wid*4 + rr;
    const float* srow = src + (row0 + r)*DD;
    float x[4];
    #pragma unroll
    for (int u=0;u<4;u++) x[u] = srow[u*64 + lane];
    for (int p=0;p<nln;p++){
      float s=0.f,q=0.f;
      #pragma unroll
      for (int u=0;u<4;u++){ s+=x[u]; q+=x[u]*x[u]; }
      #pragma unroll
      for (int o=1;o<64;o<<=1){ s+=__shfl_xor(s,o,64); q+=__shfl_xor(q,o,64); }
      float m = s*(1.f/DD), var = q*(1.f/DD)-m*m, rstd = rsqrtf(var+1e-5f);
      #pragma unroll
      for (int u=0;u<4;u++) x[u] = (x[u]-m)*rstd*gv[u]+bv[u];
    }
    if (nrmout){
      float ss=0.f;
      #pragma unroll
      for (int u=0;u<4;u++) ss += x[u]*x[u];
      #pragma unroll
      for (int o=1;o<64;o<<=1) ss += __shfl_xor(ss,o,64);
      if (lane==0) nrmout[row0 + r] = 1.f/(sqrtf(ss)+1e-6f);
    }
    if (nvout){
      #pragma unroll
      for (int u=0;u<4;u++) nvout[(row0 + r)*DD + u*64 + lane] = x[u];
    }
    #pragma unroll
    for (int u=0;u<4;u++) xs[r][u*64+lane] = x[u];
  }
  __syncthreads();

  float aU[4] = {0.f,0.f,0.f,0.f};
  float aV[4] = {0.f,0.f,0.f,0.f};
  for (int kt=0; kt<4; kt++){
    const float4* Ut = (const float4*)(U + (long)kt*64*RR);
    #pragma unroll
    for (int i=0;i<4;i++) ((float4*)ut)[i*256 + t] = Ut[i*256 + t];
    if (V){
      const float4* Vt = (const float4*)(V + (long)kt*64*RR);
      #pragma unroll
      for (int i=0;i<4;i++) ((float4*)vt)[i*256 + t] = Vt[i*256 + t];
    }
    __syncthreads();
    #pragma unroll 4
    for (int dd=0; dd<64; dd+=4){
      float4 xq[4];
      #pragma unroll
      for (int r=0;r<4;r++) xq[r] = *(const float4*)&xs[wid*4+r][kt*64+dd];
      #pragma unroll
      for (int j=0;j<4;j++){
        float uv = ut[(dd+j)*64 + lane];
        float vv = V ? vt[(dd+j)*64 + lane] : 0.f;
        #pragma unroll
        for (int r=0;r<4;r++){
          float xv = (j==0)?xq[r].x:(j==1)?xq[r].y:(j==2)?xq[r].z:xq[r].w;
          aU[r] += xv*uv;
          if (V) aV[r] += xv*vv;
        }
      }
    }
    __syncthreads();
  }
  #pragma unroll
  for (int r=0;r<4;r++){
    long row = row0 + wid*4 + r;
    ushort h, l;
    f32_split(aU[r]*scaleU, &h, &l);
    oUh[row*RR + lane] = h; oUl[row*RR + lane] = l;
    if (V){
      f32_split(aV[r]*scaleV, &h, &l);
      oVh[row*RR + lane] = h; oVl[row*RR + lane] = l;
    }
  }
}

// ======================= two-sweep fused score/top-k v2 =======================
// Swapped-operand MFMA: A = src proj (16 rows/step), B = dst proj.
// v2 microstructure: each wave holds B-frags for 64 dst (4 groups of 16) in
// registers; each A-load feeds 4 INDEPENDENT 6-MFMA chains (24 MFMA / 4 loads,
// group-interleaved issue). SPLITS=16 keeps 1024 blocks (4/CU).
// PM: 256 partials/row (split x quad x reg — disjoint src groups).  tsel folds
// 4->64 (still disjoint) then T = 16th-largest of 64 group maxes: provable
// lower bound on the true 16th |value|.  Chain accumulation order identical to
// round-4 -> scores bit-identical -> selection bit-identical.

#define SPLITS 16
#define STEPS  (NN/SPLITS/16)   // 16
#define CCAP   128

#define LOADA(AH0,AH1,AL0,AL1, STEP) { \
    const ushort* p_ = Sh + (long)(STEP)*16*RR; \
    const ushort* q_ = Sl + (long)(STEP)*16*RR; \
    AH0 = *(const bf16x8*)(p_);      AH1 = *(const bf16x8*)(p_ + 32); \
    AL0 = *(const bf16x8*)(q_);      AL1 = *(const bf16x8*)(q_ + 32); }

// 4 independent chains, group-interleaved; per-chain order matches round-4 MFMA6
#define MFMA24(AH0,AH1,AL0,AL1, A) { \
    _Pragma("unroll") for (int g=0;g<4;g++) A[g] = __builtin_amdgcn_mfma_f32_16x16x32_bf16(AH0, dh0[g], A[g], 0,0,0); \
    _Pragma("unroll") for (int g=0;g<4;g++) A[g] = __builtin_amdgcn_mfma_f32_16x16x32_bf16(AL0, dh0[g], A[g], 0,0,0); \
    _Pragma("unroll") for (int g=0;g<4;g++) A[g] = __builtin_amdgcn_mfma_f32_16x16x32_bf16(AH0, dl0[g], A[g], 0,0,0); \
    _Pragma("unroll") for (int g=0;g<4;g++) A[g] = __builtin_amdgcn_mfma_f32_16x16x32_bf16(AH1, dh1[g], A[g], 0,0,0); \
    _Pragma("unroll") for (int g=0;g<4;g++) A[g] = __builtin_amdgcn_mfma_f32_16x16x32_bf16(AL1, dh1[g], A[g], 0,0,0); \
    _Pragma("unroll") for (int g=0;g<4;g++) A[g] = __builtin_amdgcn_mfma_f32_16x16x32_bf16(AH1, dl1[g], A[g], 0,0,0); }

#define LOADB() \
  bf16x8 dh0[4], dh1[4], dl0[4], dl1[4]; \
  _Pragma("unroll") \
  for (int g=0; g<4; g++){ \
    const ushort* Dh = dph + (long)b*dp_bs + (long)(dst0 + g*16 + r16)*RR + quad*8; \
    const ushort* Dl = dpl + (long)b*dp_bs + (long)(dst0 + g*16 + r16)*RR + quad*8; \
    dh0[g] = *(const bf16x8*)(Dh);      dh1[g] = *(const bf16x8*)(Dh + 32); \
    dl0[g] = *(const bf16x8*)(Dl);      dl1[g] = *(const bf16x8*)(Dl + 32); \
  }

__global__ void __launch_bounds__(256) score_max(
    const ushort* __restrict__ dph, const ushort* __restrict__ dpl, long dp_bs,
    const ushort* __restrict__ sph, const ushort* __restrict__ spl,
    float* __restrict__ PM)
{
  const int b = blockIdx.z, split = blockIdx.y;
  const int t = threadIdx.x;
  const int w = t>>6, lane = t&63;
  const int r16 = lane&15, quad = lane>>4;
  const int dst0 = blockIdx.x*256 + w*64;
  const int src0 = split*(NN/SPLITS);

  LOADB()

  const ushort* Sh = sph + (long)b*NN*RR + (long)(src0 + r16)*RR + quad*8;
  const ushort* Sl = spl + (long)b*NN*RR + (long)(src0 + r16)*RR + quad*8;

  float pm[4][4];
  #pragma unroll
  for (int g=0;g<4;g++){ pm[g][0]=0.f; pm[g][1]=0.f; pm[g][2]=0.f; pm[g][3]=0.f; }

#define PROCM(AH0,AH1,AL0,AL1) { \
    f32x4 a[4]; \
    _Pragma("unroll") for (int g=0;g<4;g++) a[g]=(f32x4){0.f,0.f,0.f,0.f}; \
    MFMA24(AH0,AH1,AL0,AL1, a) \
    _Pragma("unroll") \
    for (int g=0;g<4;g++){ \
      pm[g][0]=fmaxf(pm[g][0],fabsf(a[g][0])); pm[g][1]=fmaxf(pm[g][1],fabsf(a[g][1])); \
      pm[g][2]=fmaxf(pm[g][2],fabsf(a[g][2])); pm[g][3]=fmaxf(pm[g][3],fabsf(a[g][3])); \
    } }

  bf16x8 xh0,xh1,xl0,xl1, yh0,yh1,yl0,yl1;
  LOADA(xh0,xh1,xl0,xl1, 0)
  for (int st=0; st<STEPS; st+=2){
    LOADA(yh0,yh1,yl0,yl1, st+1)
    PROCM(xh0,xh1,xl0,xl1)
    if (st+2 < STEPS) LOADA(xh0,xh1,xl0,xl1, st+2)
    PROCM(yh0,yh1,yl0,yl1)
  }
#undef PROCM

  #pragma unroll
  for (int g=0;g<4;g++){
    float* pmr = PM + ((long)b*NN + dst0 + g*16 + r16)*256 + split*16 + quad*4;
    pmr[0]=pm[g][0]; pmr[1]=pm[g][1]; pmr[2]=pm[g][2]; pmr[3]=pm[g][3];
  }
}

// T[row] = 16th-largest of 64 folded group-maxes (256 partials, fold 4 -> 64);
// zero CNT for collect pass
__global__ void __launch_bounds__(256) tsel_kernel(
    const float* __restrict__ PM, float* __restrict__ T, int* __restrict__ CNT)
{
  int wid = threadIdx.x>>6, lane = threadIdx.x&63;
  long g = (long)blockIdx.x*4 + wid;
  const float* pr = PM + g*256;
  float cur = fmaxf(fmaxf(pr[lane], pr[64+lane]), fmaxf(pr[128+lane], pr[192+lane]));
  float Tv = 0.f;
  for (int t=0;t<16;t++){
    float m = cur;
    #pragma unroll
    for (int o=1;o<64;o<<=1) m = fmaxf(m, __shfl_xor(m,o,64));
    Tv = m;
    unsigned long long msk = __ballot(cur == m);
    int low = __ffsll(msk) - 1;
    if (lane == low) cur = -1.f;
  }
  if (lane==0){ T[g] = Tv; CNT[g] = 0; }
}

__global__ void __launch_bounds__(256) score_collect(
    const ushort* __restrict__ dph, const ushort* __restrict__ dpl, long dp_bs,
    const ushort* __restrict__ sph, const ushort* __restrict__ spl,
    const float* __restrict__ T, int* __restrict__ CNT,
    float* __restrict__ CV, int* __restrict__ CI)
{
  const int b = blockIdx.z, split = blockIdx.y;
  const int t = threadIdx.x;
  const int w = t>>6, lane = t&63;
  const int r16 = lane&15, quad = lane>>4;
  const int dst0 = blockIdx.x*256 + w*64;
  const int src0 = split*(NN/SPLITS);

  LOADB()

  const ushort* Sh = sph + (long)b*NN*RR + (long)(src0 + r16)*RR + quad*8;
  const ushort* Sl = spl + (long)b*NN*RR + (long)(src0 + r16)*RR + quad*8;

  float Tg[4]; int* cntp[4]; float* cvp[4]; int* cip[4];
  #pragma unroll
  for (int g=0;g<4;g++){
    long row = (long)b*NN + dst0 + g*16 + r16;
    Tg[g] = T[row];
    cntp[g] = CNT + row;
    cvp[g] = CV + row*CCAP;
    cip[g] = CI + row*CCAP;
  }

#define PROCC(AH0,AH1,AL0,AL1, STEP) { \
    f32x4 a[4]; \
    _Pragma("unroll") for (int g=0;g<4;g++) a[g]=(f32x4){0.f,0.f,0.f,0.f}; \
    MFMA24(AH0,AH1,AL0,AL1, a) \
    int sbase = src0 + (STEP)*16 + quad*4; \
    _Pragma("unroll") \
    for (int g=0;g<4;g++){ \
      float m01 = fmaxf(fabsf(a[g][0]), fabsf(a[g][1])); \
      float m23 = fmaxf(fabsf(a[g][2]), fabsf(a[g][3])); \
      if (fmaxf(m01,m23) >= Tg[g]){ \
        _Pragma("unroll") \
        for (int r=0;r<4;r++){ \
          if (fabsf(a[g][r]) >= Tg[g]){ \
            int slot = atomicAdd(cntp[g], 1); \
            if (slot < CCAP){ cvp[g][slot] = a[g][r]; cip[g][slot] = sbase + r; } \
          } \
        } \
      } \
    } }

  bf16x8 xh0,xh1,xl0,xl1, yh0,yh1,yl0,yl1;
  LOADA(xh0,xh1,xl0,xl1, 0)
  for (int st=0; st<STEPS; st+=2){
    LOADA(yh0,yh1,yl0,yl1, st+1)
    PROCC(xh0,xh1,xl0,xl1, st)
    if (st+2 < STEPS) LOADA(xh0,xh1,xl0,xl1, st+2)
    PROCC(yh0,yh1,yl0,yl1, st+1)
  }
#undef PROCC
}

// final exact top-16 per row from the candidate list (or GEMV fallback)
__global__ void __launch_bounds__(256) sel16_kernel(
    const float* __restrict__ CV, const int* __restrict__ CI, const int* __restrict__ CNT,
    const ushort* __restrict__ dph, const ushort* __restrict__ dpl, long dp_bs,
    const ushort* __restrict__ sph, const ushort* __restrict__ spl,
    float* __restrict__ wout, int* __restrict__ iout)
{
  int wid = threadIdx.x>>6, lane = threadIdx.x&63;
  long g = (long)blockIdx.x*4 + wid;
  int b = (int)(g >> 12);
  int n = (int)(g & (NN-1));
  int C = CNT[g];
  long orow = g*KK;
  if (C <= CCAP){
    const float* cvp = CV + g*CCAP;
    const int*   cip = CI + g*CCAP;
    float cv0 = 0.f, cv1 = 0.f; int ci0 = 0x7fffffff, ci1 = 0x7fffffff;
    if (lane < C){ cv0 = cvp[lane]; ci0 = cip[lane]; }
    if (lane+64 < C){ cv1 = cvp[lane+64]; ci1 = cip[lane+64]; }
    float k0=fabsf(cv0), k1=fabsf(cv1);
    bool f0=(ci0==0x7fffffff), f1=(ci1==0x7fffffff);
    for (int t=0;t<KK;t++){
      float bk; int bgi; float bv;
      bool pick0 = !f0 && (f1 || k0>k1 || (k0==k1 && ci0<ci1));
      if (pick0){ bk=k0; bgi=ci0; bv=cv0; }
      else if (!f1){ bk=k1; bgi=ci1; bv=cv1; }
      else { bk=-1.f; bgi=0x7fffffff; bv=0.f; }
      #pragma unroll
      for (int o=1;o<64;o<<=1){
        float ko=__shfl_xor(bk,o,64);
        int  gio=__shfl_xor(bgi,o,64);
        float vo=__shfl_xor(bv,o,64);
        if (ko>bk || (ko==bk && gio<bgi)){ bk=ko; bgi=gio; bv=vo; }
      }
      if (lane==0){ wout[orow+t]=bv; iout[orow+t]=bgi; }
      if (!f0 && bgi==ci0) f0=true;
      else if (!f1 && bgi==ci1) f1=true;
    }
  } else {
    // degenerate row: exact re-scan (recompute scores from hi+lo projections)
    const ushort* dh = dph + (long)b*dp_bs + (long)n*RR;
    const ushort* dl = dpl + (long)b*dp_bs + (long)n*RR;
    const ushort* shb = sph + (long)b*NN*RR;
    const ushort* slb = spl + (long)b*NN*RR;
    float v[64];
    for (int j=0;j<64;j++){
      int src = lane*64 + j;
      const ushort* sh = shb + (long)src*RR;
      const ushort* sl = slb + (long)src*RR;
      float acc = 0.f;
      for (int k=0;k<RR;k++){
        float d = bf2f(dh[k]) + bf2f(dl[k]);
        float s = bf2f(sh[k]) + bf2f(sl[k]);
        acc += d*s;
      }
      v[j] = acc;
    }
    unsigned long long cons = 0ull;
    float bk=-1.f, bval=0.f; int bj=0;
    #pragma unroll
    for (int j=0;j<64;j++){
      float k = fabsf(v[j]);
      if (k > bk){ bk=k; bj=j; bval=v[j]; }
    }
    for (int t=0;t<KK;t++){
      float k = bk; int gi = lane*64 + bj; float val = bval;
      #pragma unroll
      for (int o=1;o<64;o<<=1){
        float ko = __shfl_xor(k,o,64);
        int  gio = __shfl_xor(gi,o,64);
        float vo = __shfl_xor(val,o,64);
        if (ko > k || (ko == k && gio < gi)){ k=ko; gi=gio; val=vo; }
      }
      if (lane == 0){ wout[orow+t]=val; iout[orow+t]=gi; }
      if (lane == (gi>>6)){
        cons |= 1ull << (gi & 63);
        bk=-1.f; bj=0; bval=0.f;
        #pragma unroll
        for (int j=0;j<64;j++){
          if (!((cons>>j)&1ull)){
            float kk=fabsf(v[j]);
            if (kk>bk){ bk=kk; bj=j; bval=v[j]; }
          }
        }
      }
    }
  }
}

// ---- gather + signed-softmax weights + fused apply_delta (wave per row) ----
__global__ void __launch_bounds__(256) gather_kernel(
    const float* __restrict__ wbuf, const int* __restrict__ ibuf,
    const float* __restrict__ sv, long sv_bs,
    const float* __restrict__ nrm,
    const float* __restrict__ st, long st_bs,
    const float* __restrict__ base, int base_mod,
    const float* __restrict__ bg, const float* __restrict__ bb,
    const float* __restrict__ og, const float* __restrict__ ob,
    float* __restrict__ outv, float* __restrict__ ds)
{
  int t = threadIdx.x;
  int wid = t>>6, lane = t&63;
  long row = (long)blockIdx.x*4 + wid;
  int b = (int)(row >> 12);

  int kk = lane & 15;
  int si = ibuf[row*KK + kk];
  float w = wbuf[row*KK + kk];
  float aw = fabsf(w);
  float m = aw;
  #pragma unroll
  for (int o=1;o<16;o<<=1) m = fmaxf(m, __shfl_xor(m,o,64));
  float e = expf(aw - m);
  float Z = e;
  #pragma unroll
  for (int o=1;o<16;o<<=1) Z += __shfl_xor(Z,o,64);
  float sg = (w>0.f)?1.f:((w<0.f)?-1.f:0.f);
  float vv = sg*e/Z;
  if (st){
    float stv = st[(long)b*st_bs + si];
    vv *= fmaxf(stv,0.f) + log1pf(expf(-fabsf(stv)));   // softplus
  }
  float wsum = vv;
  #pragma unroll
  for (int o=1;o<16;o<<=1) wsum += __shfl_xor(wsum,o,64);
  if (lane==0) ds[row] = wsum;
  float wkp = vv * nrm[(long)b*NN + si];

  float4 acc = {0.f,0.f,0.f,0.f};
  const float* svb = sv + (long)b*sv_bs;
  #pragma unroll
  for (int k=0;k<KK;k++){
    int   sik = __shfl(si, k, 64);
    float wk  = __shfl(wkp, k, 64);
    float4 mq = *(const float4*)(svb + (long)sik*DD + lane*4);
    acc.x += wk*mq.x; acc.y += wk*mq.y; acc.z += wk*mq.z; acc.w += wk*mq.w;
  }

  if (!base){
    *(float4*)(outv + row*DD + lane*4) = acc;
    return;
  }
  const float* brow = base + (long)(base_mod ? (row % base_mod) : row)*DD;
  float4 x4 = *(const float4*)(brow + lane*4);
  if (bg){
    float s = x4.x+x4.y+x4.z+x4.w;
    float q = x4.x*x4.x+x4.y*x4.y+x4.z*x4.z+x4.w*x4.w;
    #pragma unroll
    for (int o=1;o<64;o<<=1){ s+=__shfl_xor(s,o,64); q+=__shfl_xor(q,o,64); }
    float mm=s*(1.f/DD), var=q*(1.f/DD)-mm*mm, rstd=rsqrtf(var+1e-5f);
    float4 g4 = *(const float4*)(bg + lane*4);
    float4 b4 = *(const float4*)(bb + lane*4);
    x4.x=(x4.x-mm)*rstd*g4.x+b4.x; x4.y=(x4.y-mm)*rstd*g4.y+b4.y;
    x4.z=(x4.z-mm)*rstd*g4.z+b4.z; x4.w=(x4.w-mm)*rstd*g4.w+b4.w;
  }
  x4.x+=acc.x; x4.y+=acc.y; x4.z+=acc.z; x4.w+=acc.w;
  {
    float s = x4.x+x4.y+x4.z+x4.w;
    float q = x4.x*x4.x+x4.y*x4.y+x4.z*x4.z+x4.w*x4.w;
    #pragma unroll
    for (int o=1;o<64;o<<=1){ s+=__shfl_xor(s,o,64); q+=__shfl_xor(q,o,64); }
    float mm=s*(1.f/DD), var=q*(1.f/DD)-mm*mm, rstd=rsqrtf(var+1e-5f);
    float4 g4 = *(const float4*)(og + lane*4);
    float4 b4 = *(const float4*)(ob + lane*4);
    float4 o4;
    o4.x=(x4.x-mm)*rstd*g4.x+b4.x; o4.y=(x4.y-mm)*rstd*g4.y+b4.y;
    o4.z=(x4.z-mm)*rstd*g4.z+b4.z; o4.w=(x4.w-mm)*rstd*g4.w+b4.w;
    *(float4*)(outv + row*DD + lane*4) = o4;
  }
}

extern "C" void kernel_launch(void* const* d_in, const int* in_sizes, int n_in,
                              void* d_out, int out_size, void* d_ws, size_t ws_size,
                              hipStream_t stream)
{
  const float* b_state    = (const float*)d_in[0];
  const float* b_val      = (const float*)d_in[1];
  const float* init_state = (const float*)d_in[2];
  const float* init_val   = (const float*)d_in[3];
  const float* U_bk = (const float*)d_in[4];
  const float* V_bk = (const float*)d_in[5];
  const float* U_kb = (const float*)d_in[6];
  const float* V_kb = (const float*)d_in[7];
  const float* U_p  = (const float*)d_in[8];
  const float* V_p  = (const float*)d_in[9];
  const float* kn_g = (const float*)d_in[10];
  const float* kn_b = (const float*)d_in[11];
  const float* bn_g = (const float*)d_in[12];
  const float* bn_b = (const float*)d_in[13];
  const float* pn_g = (const float*)d_in[14];
  const float* pn_b = (const float*)d_in[15];
  float* out = (float*)d_out;

  const long o_rstate = 0;
  const long o_rval   = (long)BB*NN;
  const long o_pstate = o_rval + (long)BB*NN*DD;
  const long o_pval   = o_pstate + (long)BB*NN;
  const long o_bds    = o_pval + (long)BB*NN*DD;
  const long o_bdv    = o_bds + (long)BB*NN;

  float* RVAL = out + o_rval;
  float* PVAL = out + o_pval;
  float* RST  = out + o_rstate;
  float* PST  = out + o_pstate;

  ushort* SPh = (ushort*)d_ws;                   // [B,N,R] bf16 hi
  ushort* SPl = SPh + (long)BB*NN*RR;
  ushort* DPh = SPl + (long)BB*NN*RR;
  ushort* DPl = DPh + (long)BB*NN*RR;
  float* WB   = (float*)(DPl + (long)BB*NN*RR);  // [B,N,K]
  int*   IB   = (int*)(WB + (long)BB*NN*KK);     // [B,N,K]
  float* KST  = (float*)(IB + (long)BB*NN*KK);   // [N]
  float* DS   = KST + NN;                        // [B,N]
  float* NV   = DS + (long)BB*NN;                // [B,N,D] normalized msgs
  float* NRM  = NV + (long)BB*NN*DD;             // [B,N] 1/(||row||+1e-6)
  float* PM   = NRM + (long)BB*NN;               // [B,N,256] partial maxes
  float* TT   = PM + (long)BB*NN*256;            // [B,N] thresholds
  int*   CNT  = (int*)(TT + (long)BB*NN);        // [B,N] candidate counts
  float* CV   = (float*)(CNT + (long)BB*NN);     // [B,N,128] candidate values
  int*   CI   = (int*)(CV + (long)BB*NN*CCAP);   // [B,N,128] candidate indices

  auto run_scores = [&](long dpbs){
    score_max<<<dim3(NN/256, SPLITS, BB), 256, 0, stream>>>(DPh, DPl, dpbs, SPh, SPl, PM);
    tsel_kernel<<<BB*NN/4, 256, 0, stream>>>(PM, TT, CNT);
    score_collect<<<dim3(NN/256, SPLITS, BB), 256, 0, stream>>>(DPh, DPl, dpbs, SPh, SPl, TT, CNT, CV, CI);
    sel16_kernel<<<BB*NN/4, 256, 0, stream>>>(CV, CI, CNT, DPh, DPl, dpbs, SPh, SPl, WB, IB);
  };

  // ---- initialize_state: k_state (batch-independent) ----
  ssm_kernel<<<1,1024,0,stream>>>(init_state, 0, nullptr, 0, KST, 0);

  // ---- route_from_b: B -> K ----
  proj_ln_kernel<<<NN/TM,256,0,stream>>>(init_val, kn_g, kn_b, 2,
                                         V_bk, DPh, DPl, 0.125f, nullptr, nullptr, nullptr, 0.f,
                                         nullptr, nullptr);
  proj_ln_kernel<<<BB*NN/TM,256,0,stream>>>(b_val, nullptr, nullptr, 0,
                                            U_bk, SPh, SPl, 1.0f, nullptr, nullptr, nullptr, 0.f,
                                            nullptr, NRM);
  run_scores(0);
  gather_kernel<<<BB*NN/4,256,0,stream>>>(WB, IB,
      b_val, (long)NN*DD, NRM,
      b_state, (long)NN,
      init_val, NN, kn_g, kn_b, kn_g, kn_b,
      RVAL, DS);
  ssm_kernel<<<BB,1024,0,stream>>>(KST, 0, DS, NN, RST, NN);

  // ---- propagate ----
  proj_ln_kernel<<<BB*NN/TM,256,0,stream>>>(RVAL, pn_g, pn_b, 1,
                                            U_p, SPh, SPl, 1.0f, V_p, DPh, DPl, 0.125f,
                                            NV, NRM);
  run_scores((long)NN*RR);
  gather_kernel<<<BB*NN/4,256,0,stream>>>(WB, IB,
      NV, (long)NN*DD, NRM,
      nullptr, 0,
      RVAL, 0, nullptr, nullptr, kn_g, kn_b,
      PVAL, DS);
  ssm_kernel<<<BB,1024,0,stream>>>(RST, NN, DS, NN, PST, NN);

  // ---- transition_to_b: K -> B ----
  proj_ln_kernel<<<BB*NN/TM,256,0,stream>>>(PVAL, kn_g, kn_b, 1,
                                            U_kb, SPh, SPl, 1.0f, nullptr, nullptr, nullptr, 0.f,
                                            NV, NRM);
  proj_ln_kernel<<<BB*NN/TM,256,0,stream>>>(b_val, bn_g, bn_b, 1,
                                            V_kb, DPh, DPl, 0.125f, nullptr, nullptr, nullptr, 0.f,
                                            nullptr, nullptr);
  run_scores((long)NN*RR);
  gather_kernel<<<BB*NN/4,256,0,stream>>>(WB, IB,
      NV, (long)NN*DD, NRM,
      PST, (long)NN,
      nullptr, 0, nullptr, nullptr, nullptr, nullptr,
      out + o_bdv, out + o_bds);
}